// Round 3
// baseline (796.506 us; speedup 1.0000x reference)
//
#include <hip/hip_runtime.h>

#define WIDTH 128
#define SLOPE 0.01f
#define SBS 512           // scan/sum block size
#define FROWS 8           // rows per fused block (1 wave each, 512 threads)

// ---------------- CSR build: counting sort of edges by dst ----------------
// hist: counts[dst]++ and record each edge's rank within its dst segment.
__global__ void hist_kernel(const int* __restrict__ e,
                            unsigned* __restrict__ counts,
                            int* __restrict__ rank, int E) {
    int i = blockIdx.x * blockDim.x + threadIdx.x;
    if (i < E) {
        int dst = e[E + i];
        rank[i] = (int)atomicAdd(&counts[dst], 1u);
    }
}

// Stage 1: per-block sums of counts (coalesced).
__global__ void block_sum_kernel(const unsigned* __restrict__ counts,
                                 unsigned* __restrict__ bsums, int M) {
    int i = blockIdx.x * SBS + threadIdx.x;
    unsigned v = (i < M) ? counts[i] : 0u;
    for (int d = 32; d > 0; d >>= 1) v += __shfl_down(v, d);
    __shared__ unsigned ws[SBS / 64];
    int lane = threadIdx.x & 63, w = threadIdx.x >> 6;
    if (lane == 0) ws[w] = v;
    __syncthreads();
    if (threadIdx.x == 0) {
        unsigned s = 0;
        for (int k = 0; k < SBS / 64; ++k) s += ws[k];
        bsums[blockIdx.x] = s;
    }
}

// Stage 2: exclusive scan of the (<=256) block sums; also writes offsets[M]=E.
__global__ void bsum_scan_kernel(const unsigned* __restrict__ bsums,
                                 unsigned* __restrict__ bbase, int NB,
                                 int* __restrict__ offsets, int M) {
    __shared__ unsigned s[256];
    int t = threadIdx.x;
    unsigned v = (t < NB) ? bsums[t] : 0u;
    s[t] = v;
    __syncthreads();
    for (int off = 1; off < 256; off <<= 1) {
        unsigned n = (t >= off) ? s[t - off] : 0u;
        __syncthreads();
        s[t] += n;
        __syncthreads();
    }
    if (t < NB) bbase[t] = s[t] - v;          // exclusive prefix
    if (t == 255) offsets[M] = (int)s[255];   // total == E
}

// Stage 3: per-block coalesced scan -> global exclusive offsets.
__global__ void scan_final_kernel(const unsigned* __restrict__ counts,
                                  const unsigned* __restrict__ bbase,
                                  int* __restrict__ offsets, int M) {
    int b = blockIdx.x, t = threadIdx.x;
    int i = b * SBS + t;
    unsigned c = (i < M) ? counts[i] : 0u;
    unsigned v = c;
    int lane = t & 63, w = t >> 6;
    for (int d = 1; d < 64; d <<= 1) {
        unsigned n = __shfl_up(v, d);
        if (lane >= d) v += n;
    }
    __shared__ unsigned ws[SBS / 64];
    if (lane == 63) ws[w] = v;
    __syncthreads();
    unsigned wbase = 0;
    for (int k = 0; k < w; ++k) wbase += ws[k];
    if (i < M) offsets[i] = (int)(bbase[b] + wbase + v - c);
}

// Scatter without atomics: slot = offsets[dst] + rank (unique per edge).
__global__ void scatter_kernel(const int* __restrict__ e,
                               const int* __restrict__ offsets,
                               const int* __restrict__ rank,
                               int* __restrict__ csr_src, int E) {
    int i = blockIdx.x * blockDim.x + threadIdx.x;
    if (i < E) {
        int dst = e[E + i];
        csr_src[offsets[dst] + rank[i]] = e[i];
    }
}

// ---------------- Fused: register min-reduce + MLP + residual ----------------
// One 64-lane wave per dst row, float2 per lane.
// maxes = (deg>0 ? x_dst - min_{edges}(x_src) : 0)   [exact]
// out   = x_dst + leaky_relu([x_dst, maxes] @ W + b)
__global__ void fused_kernel(const float* __restrict__ x_src,
                             const float* __restrict__ x_dst,
                             const int* __restrict__ offsets,
                             const int* __restrict__ csr_src,
                             const float* __restrict__ Wg,
                             const float* __restrict__ bias,
                             float* __restrict__ out, int M) {
    __shared__ float cat[FROWS][2 * WIDTH];
    int lane = threadIdx.x & 63;
    int w = threadIdx.x >> 6;           // wave id == row slot
    int row = blockIdx.x * FROWS + w;
    bool active = (row < M);

    int beg = 0, end = 0;
    if (active) { beg = offsets[row]; end = offsets[row + 1]; }
    int deg = end - beg;

    const float2* xs2 = reinterpret_cast<const float2*>(x_src);
    float2 mn = make_float2(INFINITY, INFINITY);
    for (int base = 0; base < deg; base += 64) {
        int navail = min(64, deg - base);
        // clamped cooperative index load: lanes >= navail hold a duplicate
        int idx = csr_src[beg + base + min(lane, navail - 1)];
        for (int j = 0; j < navail; j += 4) {
            int s0 = __shfl(idx, j);
            int s1 = __shfl(idx, j + 1);   // dups past navail-1: harmless (min idempotent)
            int s2 = __shfl(idx, j + 2);
            int s3 = __shfl(idx, j + 3);
            float2 v0 = xs2[(size_t)s0 * 64 + lane];
            float2 v1 = xs2[(size_t)s1 * 64 + lane];
            float2 v2 = xs2[(size_t)s2 * 64 + lane];
            float2 v3 = xs2[(size_t)s3 * 64 + lane];
            v0.x = fminf(v0.x, v1.x); v0.y = fminf(v0.y, v1.y);
            v2.x = fminf(v2.x, v3.x); v2.y = fminf(v2.y, v3.y);
            mn.x = fminf(mn.x, fminf(v0.x, v2.x));
            mn.y = fminf(mn.y, fminf(v0.y, v2.y));
        }
    }

    float2 xd = make_float2(0.f, 0.f);
    if (active) xd = reinterpret_cast<const float2*>(x_dst)[(size_t)row * 64 + lane];
    float2 mx = make_float2(0.f, 0.f);
    if (deg > 0) { mx.x = xd.x - mn.x; mx.y = xd.y - mn.y; }

    if (active) {
        reinterpret_cast<float2*>(&cat[w][0])[lane] = xd;
        reinterpret_cast<float2*>(&cat[w][WIDTH])[lane] = mx;
    }
    __syncthreads();

    if (active) {
        float2 acc = reinterpret_cast<const float2*>(bias)[lane];
        const float2* W2 = reinterpret_cast<const float2*>(Wg);
        #pragma unroll 8
        for (int k = 0; k < 2 * WIDTH; ++k) {
            float a = cat[w][k];                 // LDS broadcast
            float2 wv = W2[(size_t)k * 64 + lane];
            acc.x = fmaf(a, wv.x, acc.x);
            acc.y = fmaf(a, wv.y, acc.y);
        }
        float2 r;
        r.x = xd.x + (acc.x > 0.0f ? acc.x : SLOPE * acc.x);
        r.y = xd.y + (acc.y > 0.0f ? acc.y : SLOPE * acc.y);
        reinterpret_cast<float2*>(out)[(size_t)row * 64 + lane] = r;
    }
}

extern "C" void kernel_launch(void* const* d_in, const int* in_sizes, int n_in,
                              void* d_out, int out_size, void* d_ws, size_t ws_size,
                              hipStream_t stream) {
    const float* x_src = (const float*)d_in[0];
    const float* x_dst = (const float*)d_in[1];
    const int*   e     = (const int*)d_in[2];
    const float* W     = (const float*)d_in[3];
    const float* bias  = (const float*)d_in[4];
    float* out = (float*)d_out;

    int E = in_sizes[2] / 2;       // 800000
    int M = in_sizes[1] / WIDTH;   // 100000 dst nodes
    int NB = (M + SBS - 1) / SBS;  // 196 scan blocks (<= 256)

    // Workspace (4B each): counts[M] | offsets[M+1] | rank[E] | csr_src[E] | bsums[NB] | bbase[NB]
    unsigned* counts  = (unsigned*)d_ws;
    int*      offsets = (int*)(counts + M);
    int*      rank    = offsets + (M + 1);
    int*      csr_src = rank + E;
    unsigned* bsums   = (unsigned*)(csr_src + E);
    unsigned* bbase   = bsums + NB;

    hipMemsetAsync(counts, 0, (size_t)M * sizeof(unsigned), stream);

    int eblocks = (E + 255) / 256;
    hist_kernel<<<eblocks, 256, 0, stream>>>(e, counts, rank, E);
    block_sum_kernel<<<NB, SBS, 0, stream>>>(counts, bsums, M);
    bsum_scan_kernel<<<1, 256, 0, stream>>>(bsums, bbase, NB, offsets, M);
    scan_final_kernel<<<NB, SBS, 0, stream>>>(counts, bbase, offsets, M);
    scatter_kernel<<<eblocks, 256, 0, stream>>>(e, offsets, rank, csr_src, E);

    int fblocks = (M + FROWS - 1) / FROWS;
    fused_kernel<<<fblocks, FROWS * 64, 0, stream>>>(x_src, x_dst, offsets, csr_src,
                                                     W, bias, out, M);
}

// Round 4
// 225.556 us; speedup vs baseline: 3.5313x; 3.5313x over previous
//
#include <hip/hip_runtime.h>

#define WIDTH 128
#define SLOPE 0.01f
#define SBS 512           // scan/sum block size
#define GWAVES 8          // waves per gather block
#define BM 128
#define BK 32

__device__ __forceinline__ float bf2f(unsigned short u) {
    return __uint_as_float(((unsigned)u) << 16);
}
__device__ __forceinline__ unsigned short f2bf(float f) {
    unsigned b = __float_as_uint(f);
    b += 0x7FFFu + ((b >> 16) & 1u);   // round-to-nearest-even
    return (unsigned short)(b >> 16);
}

// ---------------- CSR build: counting sort of edges by dst ----------------
__global__ void hist_kernel(const int* __restrict__ e,
                            unsigned* __restrict__ counts,
                            int* __restrict__ rank, int E) {
    int i = blockIdx.x * blockDim.x + threadIdx.x;
    if (i < E) {
        int dst = e[E + i];
        rank[i] = (int)atomicAdd(&counts[dst], 1u);
    }
}

__global__ void block_sum_kernel(const unsigned* __restrict__ counts,
                                 unsigned* __restrict__ bsums, int M) {
    int i = blockIdx.x * SBS + threadIdx.x;
    unsigned v = (i < M) ? counts[i] : 0u;
    for (int d = 32; d > 0; d >>= 1) v += __shfl_down(v, d);
    __shared__ unsigned ws[SBS / 64];
    int lane = threadIdx.x & 63, w = threadIdx.x >> 6;
    if (lane == 0) ws[w] = v;
    __syncthreads();
    if (threadIdx.x == 0) {
        unsigned s = 0;
        for (int k = 0; k < SBS / 64; ++k) s += ws[k];
        bsums[blockIdx.x] = s;
    }
}

__global__ void bsum_scan_kernel(const unsigned* __restrict__ bsums,
                                 unsigned* __restrict__ bbase, int NB,
                                 int* __restrict__ offsets, int M) {
    __shared__ unsigned s[256];
    int t = threadIdx.x;
    unsigned v = (t < NB) ? bsums[t] : 0u;
    s[t] = v;
    __syncthreads();
    for (int off = 1; off < 256; off <<= 1) {
        unsigned n = (t >= off) ? s[t - off] : 0u;
        __syncthreads();
        s[t] += n;
        __syncthreads();
    }
    if (t < NB) bbase[t] = s[t] - v;
    if (t == 255) offsets[M] = (int)s[255];
}

__global__ void scan_final_kernel(const unsigned* __restrict__ counts,
                                  const unsigned* __restrict__ bbase,
                                  int* __restrict__ offsets, int M) {
    int b = blockIdx.x, t = threadIdx.x;
    int i = b * SBS + t;
    unsigned c = (i < M) ? counts[i] : 0u;
    unsigned v = c;
    int lane = t & 63, w = t >> 6;
    for (int d = 1; d < 64; d <<= 1) {
        unsigned n = __shfl_up(v, d);
        if (lane >= d) v += n;
    }
    __shared__ unsigned ws[SBS / 64];
    if (lane == 63) ws[w] = v;
    __syncthreads();
    unsigned wbase = 0;
    for (int k = 0; k < w; ++k) wbase += ws[k];
    if (i < M) offsets[i] = (int)(bbase[b] + wbase + v - c);
}

__global__ void scatter_kernel(const int* __restrict__ e,
                               const int* __restrict__ offsets,
                               const int* __restrict__ rank,
                               int* __restrict__ csr_src, int E) {
    int i = blockIdx.x * blockDim.x + threadIdx.x;
    if (i < E) {
        int dst = e[E + i];
        csr_src[offsets[dst] + rank[i]] = e[i];
    }
}

// ---------------- Gather + min, write maxes (bf16) ----------------
// One wave per dst row. 8 edges/iteration: scalar-uniform index loads,
// 4 independent dwordx4 gathers (lane halves cover 2 edges each).
__global__ void gather_min_kernel(const float* __restrict__ x_src,
                                  const float* __restrict__ x_dst,
                                  const int* __restrict__ offsets,
                                  const int* __restrict__ csr_src,
                                  unsigned short* __restrict__ maxes,
                                  int M) {
    int lane = threadIdx.x & 63;
    int row = blockIdx.x * GWAVES + (threadIdx.x >> 6);
    row = __builtin_amdgcn_readfirstlane(row);   // force SGPR -> s_loads below
    if (row >= M) return;
    int beg = offsets[row];
    int end = offsets[row + 1];
    int half = lane >> 5;
    int cl = lane & 31;

    const float4* xs4 = reinterpret_cast<const float4*>(x_src);
    float4 mn = make_float4(INFINITY, INFINITY, INFINITY, INFINITY);
    for (int base = beg; base < end; base += 8) {
        int lim = end - 1;
        int s0 = csr_src[base];
        int s1 = csr_src[min(base + 1, lim)];
        int s2 = csr_src[min(base + 2, lim)];
        int s3 = csr_src[min(base + 3, lim)];
        int s4 = csr_src[min(base + 4, lim)];
        int s5 = csr_src[min(base + 5, lim)];
        int s6 = csr_src[min(base + 6, lim)];
        int s7 = csr_src[min(base + 7, lim)];
        int a0 = half ? s1 : s0;     // duplicates past end are harmless (min idempotent)
        int a1 = half ? s3 : s2;
        int a2 = half ? s5 : s4;
        int a3 = half ? s7 : s6;
        float4 v0 = xs4[(size_t)a0 * 32 + cl];
        float4 v1 = xs4[(size_t)a1 * 32 + cl];
        float4 v2 = xs4[(size_t)a2 * 32 + cl];
        float4 v3 = xs4[(size_t)a3 * 32 + cl];
        v0.x = fminf(v0.x, v1.x); v0.y = fminf(v0.y, v1.y);
        v0.z = fminf(v0.z, v1.z); v0.w = fminf(v0.w, v1.w);
        v2.x = fminf(v2.x, v3.x); v2.y = fminf(v2.y, v3.y);
        v2.z = fminf(v2.z, v3.z); v2.w = fminf(v2.w, v3.w);
        mn.x = fminf(mn.x, fminf(v0.x, v2.x));
        mn.y = fminf(mn.y, fminf(v0.y, v2.y));
        mn.z = fminf(mn.z, fminf(v0.z, v2.z));
        mn.w = fminf(mn.w, fminf(v0.w, v2.w));
    }
    // fold the two halves (each processed different edges, same columns)
    mn.x = fminf(mn.x, __shfl_xor(mn.x, 32));
    mn.y = fminf(mn.y, __shfl_xor(mn.y, 32));
    mn.z = fminf(mn.z, __shfl_xor(mn.z, 32));
    mn.w = fminf(mn.w, __shfl_xor(mn.w, 32));

    if (lane < 32) {
        ushort4 o;
        if (end > beg) {
            float4 xd = reinterpret_cast<const float4*>(x_dst)[(size_t)row * 32 + cl];
            o.x = f2bf(xd.x - mn.x);
            o.y = f2bf(xd.y - mn.y);
            o.z = f2bf(xd.z - mn.z);
            o.w = f2bf(xd.w - mn.w);
        } else {
            o.x = o.y = o.z = o.w = 0;
        }
        reinterpret_cast<ushort4*>(maxes)[(size_t)row * 32 + cl] = o;
    }
}

// ---------------- Tiled GEMM: out = x_dst + lrelu([x_dst|maxes] @ W + b) ----
// 128x128 block tile, BK=32, 256 threads, 8x8 register tile/thread.
// W staged in LDS once per 128 rows (kills the 13 GB L2 W-re-read).
__global__ __launch_bounds__(256) void mlp_gemm_kernel(
        const float* __restrict__ x_dst,
        const unsigned short* __restrict__ maxes,
        const float* __restrict__ Wg,
        const float* __restrict__ bias,
        float* __restrict__ out, int M) {
    __shared__ float As[BK][132];   // [k][m], padded to 132 (16B-aligned rows)
    __shared__ float Ws[BK][128];   // [k][n]
    int tid = threadIdx.x;
    int tn = tid & 15;              // 16 col-threads
    int tm = tid >> 4;              // 16 row-threads
    int blockRow = blockIdx.x * BM;

    float acc[8][8];
    #pragma unroll
    for (int i = 0; i < 8; ++i)
        #pragma unroll
        for (int j = 0; j < 8; ++j) acc[i][j] = 0.0f;

    for (int c = 0; c < 2 * WIDTH / BK; ++c) {
        int kbase = c * BK;
        __syncthreads();
        // stage A tile (transposed): As[k][m]
        {
            int kq = (tid & 7) * 4;
            int mrow = tid >> 3;    // 0..31
            #pragma unroll
            for (int p = 0; p < 4; ++p) {
                int m = mrow + 32 * p;
                int gr = min(blockRow + m, M - 1);   // clamp; stores are guarded
                float4 v;
                if (kbase < WIDTH) {
                    v = *reinterpret_cast<const float4*>(
                        x_dst + (size_t)gr * WIDTH + kbase + kq);
                } else {
                    ushort4 u = *reinterpret_cast<const ushort4*>(
                        maxes + (size_t)gr * WIDTH + (kbase - WIDTH) + kq);
                    v = make_float4(bf2f(u.x), bf2f(u.y), bf2f(u.z), bf2f(u.w));
                }
                As[kq + 0][m] = v.x;
                As[kq + 1][m] = v.y;
                As[kq + 2][m] = v.z;
                As[kq + 3][m] = v.w;
            }
        }
        // stage W tile: contiguous copy
        {
            const float4* src = reinterpret_cast<const float4*>(Wg + (size_t)kbase * WIDTH);
            float4* dst = reinterpret_cast<float4*>(&Ws[0][0]);
            #pragma unroll
            for (int p = 0; p < 4; ++p) dst[tid + 256 * p] = src[tid + 256 * p];
        }
        __syncthreads();

        #pragma unroll 4
        for (int k = 0; k < BK; ++k) {
            float4 a0 = *reinterpret_cast<const float4*>(&As[k][tm * 4]);
            float4 a1 = *reinterpret_cast<const float4*>(&As[k][64 + tm * 4]);
            float4 w0 = *reinterpret_cast<const float4*>(&Ws[k][tn * 4]);
            float4 w1 = *reinterpret_cast<const float4*>(&Ws[k][64 + tn * 4]);
            const float av[8] = {a0.x, a0.y, a0.z, a0.w, a1.x, a1.y, a1.z, a1.w};
            const float wv[8] = {w0.x, w0.y, w0.z, w0.w, w1.x, w1.y, w1.z, w1.w};
            #pragma unroll
            for (int ri = 0; ri < 8; ++ri)
                #pragma unroll
                for (int cj = 0; cj < 8; ++cj)
                    acc[ri][cj] = fmaf(av[ri], wv[cj], acc[ri][cj]);
        }
    }

    // epilogue: h = acc + b; out = x_dst + lrelu(h)
    float4 bb0 = reinterpret_cast<const float4*>(bias)[tn];
    float4 bb1 = reinterpret_cast<const float4*>(bias)[16 + tn];
    const float bv[8] = {bb0.x, bb0.y, bb0.z, bb0.w, bb1.x, bb1.y, bb1.z, bb1.w};
    const float4* xd4 = reinterpret_cast<const float4*>(x_dst);
    float4* out4 = reinterpret_cast<float4*>(out);
    #pragma unroll
    for (int ri = 0; ri < 8; ++ri) {
        int m = (ri < 4) ? (tm * 4 + ri) : (64 + tm * 4 + (ri - 4));
        int row = blockRow + m;
        if (row < M) {
            float4 xd0 = xd4[(size_t)row * 32 + tn];
            float4 xd1 = xd4[(size_t)row * 32 + 16 + tn];
            float4 r0, r1;
            float h;
            h = acc[ri][0] + bv[0]; r0.x = xd0.x + (h > 0.f ? h : SLOPE * h);
            h = acc[ri][1] + bv[1]; r0.y = xd0.y + (h > 0.f ? h : SLOPE * h);
            h = acc[ri][2] + bv[2]; r0.z = xd0.z + (h > 0.f ? h : SLOPE * h);
            h = acc[ri][3] + bv[3]; r0.w = xd0.w + (h > 0.f ? h : SLOPE * h);
            h = acc[ri][4] + bv[4]; r1.x = xd1.x + (h > 0.f ? h : SLOPE * h);
            h = acc[ri][5] + bv[5]; r1.y = xd1.y + (h > 0.f ? h : SLOPE * h);
            h = acc[ri][6] + bv[6]; r1.z = xd1.z + (h > 0.f ? h : SLOPE * h);
            h = acc[ri][7] + bv[7]; r1.w = xd1.w + (h > 0.f ? h : SLOPE * h);
            out4[(size_t)row * 32 + tn] = r0;
            out4[(size_t)row * 32 + 16 + tn] = r1;
        }
    }
}

extern "C" void kernel_launch(void* const* d_in, const int* in_sizes, int n_in,
                              void* d_out, int out_size, void* d_ws, size_t ws_size,
                              hipStream_t stream) {
    const float* x_src = (const float*)d_in[0];
    const float* x_dst = (const float*)d_in[1];
    const int*   e     = (const int*)d_in[2];
    const float* W     = (const float*)d_in[3];
    const float* bias  = (const float*)d_in[4];
    float* out = (float*)d_out;

    int E = in_sizes[2] / 2;        // 800000
    int M = in_sizes[1] / WIDTH;    // 100000 dst nodes
    int NB = (M + SBS - 1) / SBS;   // 196 (<= 256)

    // ws layout: maxes(bf16)[M*128] | counts[M] | offsets[M+1] | rank[E] | csr_src[E] | bsums | bbase
    unsigned short* maxes = (unsigned short*)d_ws;
    unsigned* counts  = (unsigned*)(maxes + (size_t)M * WIDTH);
    int*      offsets = (int*)(counts + M);
    int*      rank    = offsets + (M + 1);
    int*      csr_src = rank + E;
    unsigned* bsums   = (unsigned*)(csr_src + E);
    unsigned* bbase   = bsums + NB;

    hipMemsetAsync(counts, 0, (size_t)M * sizeof(unsigned), stream);

    int eblocks = (E + 255) / 256;
    hist_kernel<<<eblocks, 256, 0, stream>>>(e, counts, rank, E);
    block_sum_kernel<<<NB, SBS, 0, stream>>>(counts, bsums, M);
    bsum_scan_kernel<<<1, 256, 0, stream>>>(bsums, bbase, NB, offsets, M);
    scan_final_kernel<<<NB, SBS, 0, stream>>>(counts, bbase, offsets, M);
    scatter_kernel<<<eblocks, 256, 0, stream>>>(e, offsets, rank, csr_src, E);

    int gblocks = (M + GWAVES - 1) / GWAVES;
    gather_min_kernel<<<gblocks, GWAVES * 64, 0, stream>>>(x_src, x_dst, offsets,
                                                           csr_src, maxes, M);

    int mblocks = (M + BM - 1) / BM;
    mlp_gemm_kernel<<<mblocks, 256, 0, stream>>>(x_dst, maxes, W, bias, out, M);
}

// Round 5
// 200.835 us; speedup vs baseline: 3.9660x; 1.1231x over previous
//
#include <hip/hip_runtime.h>

#define WIDTH 128
#define SLOPE 0.01f
#define SBS 512
#define GWAVES 8
#define GBM 64

typedef __attribute__((ext_vector_type(8))) short short8;
typedef __attribute__((ext_vector_type(4))) float f32x4;

__device__ __forceinline__ unsigned short f2bf(float f) {
    unsigned b = __float_as_uint(f);
    b += 0x7FFFu + ((b >> 16) & 1u);   // round-to-nearest-even
    return (unsigned short)(b >> 16);
}

// ---------------- CSR build: counting sort of edges by dst ----------------
__global__ void hist_kernel(const int* __restrict__ e,
                            unsigned* __restrict__ counts,
                            int* __restrict__ rank, int E) {
    int i = blockIdx.x * blockDim.x + threadIdx.x;
    if (i < E) {
        int dst = e[E + i];
        rank[i] = (int)atomicAdd(&counts[dst], 1u);
    }
}

__global__ void block_sum_kernel(const unsigned* __restrict__ counts,
                                 unsigned* __restrict__ bsums, int M) {
    int i = blockIdx.x * SBS + threadIdx.x;
    unsigned v = (i < M) ? counts[i] : 0u;
    for (int d = 32; d > 0; d >>= 1) v += __shfl_down(v, d);
    __shared__ unsigned ws[SBS / 64];
    int lane = threadIdx.x & 63, w = threadIdx.x >> 6;
    if (lane == 0) ws[w] = v;
    __syncthreads();
    if (threadIdx.x == 0) {
        unsigned s = 0;
        for (int k = 0; k < SBS / 64; ++k) s += ws[k];
        bsums[blockIdx.x] = s;
    }
}

__global__ void bsum_scan_kernel(const unsigned* __restrict__ bsums,
                                 unsigned* __restrict__ bbase, int NB,
                                 int* __restrict__ offsets, int M) {
    __shared__ unsigned s[256];
    int t = threadIdx.x;
    unsigned v = (t < NB) ? bsums[t] : 0u;
    s[t] = v;
    __syncthreads();
    for (int off = 1; off < 256; off <<= 1) {
        unsigned n = (t >= off) ? s[t - off] : 0u;
        __syncthreads();
        s[t] += n;
        __syncthreads();
    }
    if (t < NB) bbase[t] = s[t] - v;
    if (t == 255) offsets[M] = (int)s[255];
}

__global__ void scan_final_kernel(const unsigned* __restrict__ counts,
                                  const unsigned* __restrict__ bbase,
                                  int* __restrict__ offsets, int M) {
    int b = blockIdx.x, t = threadIdx.x;
    int i = b * SBS + t;
    unsigned c = (i < M) ? counts[i] : 0u;
    unsigned v = c;
    int lane = t & 63, w = t >> 6;
    for (int d = 1; d < 64; d <<= 1) {
        unsigned n = __shfl_up(v, d);
        if (lane >= d) v += n;
    }
    __shared__ unsigned ws[SBS / 64];
    if (lane == 63) ws[w] = v;
    __syncthreads();
    unsigned wbase = 0;
    for (int k = 0; k < w; ++k) wbase += ws[k];
    if (i < M) offsets[i] = (int)(bbase[b] + wbase + v - c);
}

__global__ void scatter_kernel(const int* __restrict__ e,
                               const int* __restrict__ offsets,
                               const int* __restrict__ rank,
                               int* __restrict__ csr_src, int E) {
    int i = blockIdx.x * blockDim.x + threadIdx.x;
    if (i < E) {
        int dst = e[E + i];
        csr_src[offsets[dst] + rank[i]] = e[i];
    }
}

// ---------------- W transpose + bf16: Wt[n][k] = bf16(W[k][n]) -------------
__global__ void wt_kernel(const float* __restrict__ W,
                          unsigned short* __restrict__ Wt) {
    int t = blockIdx.x * blockDim.x + threadIdx.x;
    if (t >= 128 * 64) return;
    int n = t & 127, kc = t >> 7;   // kc: 0..63 (4 k's each)
    ushort4 o;
    o.x = f2bf(W[(size_t)(kc * 4 + 0) * 128 + n]);
    o.y = f2bf(W[(size_t)(kc * 4 + 1) * 128 + n]);
    o.z = f2bf(W[(size_t)(kc * 4 + 2) * 128 + n]);
    o.w = f2bf(W[(size_t)(kc * 4 + 3) * 128 + n]);
    *reinterpret_cast<ushort4*>(Wt + (size_t)n * 256 + kc * 4) = o;
}

// ---------------- Gather + min -> maxes (bf16) -----------------------------
// One wave per dst row; 2 edges per gather instruction (lane halves),
// 4 pairs per iteration with wave-uniform gating (no wasted gathers).
__global__ void gather_min_kernel(const float* __restrict__ x_src,
                                  const float* __restrict__ x_dst,
                                  const int* __restrict__ offsets,
                                  const int* __restrict__ csr_src,
                                  unsigned short* __restrict__ maxes,
                                  int M) {
    int lane = threadIdx.x & 63;
    int row = blockIdx.x * GWAVES + (threadIdx.x >> 6);
    row = __builtin_amdgcn_readfirstlane(row);   // uniform -> scalar loads
    if (row >= M) return;
    int beg = offsets[row];
    int end = offsets[row + 1];
    int deg = end - beg;
    int half = lane >> 5;
    int cl = lane & 31;

    float4 xd = reinterpret_cast<const float4*>(x_dst)[(size_t)row * 32 + cl];

    const float4* xs4 = reinterpret_cast<const float4*>(x_src);
    float4 mn = make_float4(INFINITY, INFINITY, INFINITY, INFINITY);
    float4 mn2 = mn;
    int npairs = (deg + 1) >> 1;
    int lim = end - 1;
    for (int p = 0; p < npairs; p += 4) {
        int base = beg + 2 * p;
        int rem = npairs - p;                    // wave-uniform
        int s0 = csr_src[base];
        int s1 = csr_src[min(base + 1, lim)];
        float4 v0 = xs4[(size_t)(half ? s1 : s0) * 32 + cl];
        mn.x = fminf(mn.x, v0.x); mn.y = fminf(mn.y, v0.y);
        mn.z = fminf(mn.z, v0.z); mn.w = fminf(mn.w, v0.w);
        if (rem > 1) {
            int s2 = csr_src[base + 2];
            int s3 = csr_src[min(base + 3, lim)];
            float4 v1 = xs4[(size_t)(half ? s3 : s2) * 32 + cl];
            mn2.x = fminf(mn2.x, v1.x); mn2.y = fminf(mn2.y, v1.y);
            mn2.z = fminf(mn2.z, v1.z); mn2.w = fminf(mn2.w, v1.w);
        }
        if (rem > 2) {
            int s4 = csr_src[base + 4];
            int s5 = csr_src[min(base + 5, lim)];
            float4 v2 = xs4[(size_t)(half ? s5 : s4) * 32 + cl];
            mn.x = fminf(mn.x, v2.x); mn.y = fminf(mn.y, v2.y);
            mn.z = fminf(mn.z, v2.z); mn.w = fminf(mn.w, v2.w);
        }
        if (rem > 3) {
            int s6 = csr_src[base + 6];
            int s7 = csr_src[min(base + 7, lim)];
            float4 v3 = xs4[(size_t)(half ? s7 : s6) * 32 + cl];
            mn2.x = fminf(mn2.x, v3.x); mn2.y = fminf(mn2.y, v3.y);
            mn2.z = fminf(mn2.z, v3.z); mn2.w = fminf(mn2.w, v3.w);
        }
    }
    mn.x = fminf(mn.x, mn2.x); mn.y = fminf(mn.y, mn2.y);
    mn.z = fminf(mn.z, mn2.z); mn.w = fminf(mn.w, mn2.w);
    // fold the two 32-lane halves (different edges, same columns)
    mn.x = fminf(mn.x, __shfl_xor(mn.x, 32));
    mn.y = fminf(mn.y, __shfl_xor(mn.y, 32));
    mn.z = fminf(mn.z, __shfl_xor(mn.z, 32));
    mn.w = fminf(mn.w, __shfl_xor(mn.w, 32));

    if (lane < 32) {
        ushort4 o;
        if (deg > 0) {
            o.x = f2bf(xd.x - mn.x);
            o.y = f2bf(xd.y - mn.y);
            o.z = f2bf(xd.z - mn.z);
            o.w = f2bf(xd.w - mn.w);
        } else {
            o.x = o.y = o.z = o.w = 0;
        }
        reinterpret_cast<ushort4*>(maxes)[(size_t)row * 32 + cl] = o;
    }
}

// ---------------- MFMA GEMM: out = x_dst + lrelu([x_dst|maxes]@W + b) ------
// 64 rows/block, 4 waves each owning a 32-col slice. No LDS: A-frags direct
// from global (32KB/block working set, L1-resident), B-frags from Wt (64KB,
// L2-resident). mfma_f32_16x16x32_bf16; A row=lane&15, k=8*(lane>>4)+i;
// B(Wt) col=lane&15, same k; C col=lane&15, row=4*(lane>>4)+r  [m89-verified]
__global__ __launch_bounds__(256) void mfma_gemm_kernel(
        const float* __restrict__ x_dst,
        const unsigned short* __restrict__ maxes,
        const unsigned short* __restrict__ Wt,
        const float* __restrict__ bias,
        float* __restrict__ out, int M) {
    int lane = threadIdx.x & 63;
    int wv = threadIdx.x >> 6;     // 0..3
    int l15 = lane & 15;
    int q = lane >> 4;             // 0..3
    int blockRow = blockIdx.x * GBM;
    int ncol0 = wv * 32;

    f32x4 acc[4][2];
    #pragma unroll
    for (int t = 0; t < 4; ++t) {
        acc[t][0] = (f32x4){0.f, 0.f, 0.f, 0.f};
        acc[t][1] = (f32x4){0.f, 0.f, 0.f, 0.f};
    }

    int rA[4];
    #pragma unroll
    for (int t = 0; t < 4; ++t) rA[t] = min(blockRow + t * 16 + l15, M - 1);

    #pragma unroll
    for (int s = 0; s < 8; ++s) {
        int koff = s * 32 + q * 8;
        short8 b0 = *reinterpret_cast<const short8*>(
            Wt + (size_t)(ncol0 + l15) * 256 + koff);
        short8 b1 = *reinterpret_cast<const short8*>(
            Wt + (size_t)(ncol0 + 16 + l15) * 256 + koff);
        #pragma unroll
        for (int t = 0; t < 4; ++t) {
            short8 a;
            if (s < 4) {   // k<128: x_dst f32, convert on the fly
                const float* src = x_dst + (size_t)rA[t] * WIDTH + koff;
                float4 lo = *reinterpret_cast<const float4*>(src);
                float4 hi = *reinterpret_cast<const float4*>(src + 4);
                a[0] = (short)f2bf(lo.x); a[1] = (short)f2bf(lo.y);
                a[2] = (short)f2bf(lo.z); a[3] = (short)f2bf(lo.w);
                a[4] = (short)f2bf(hi.x); a[5] = (short)f2bf(hi.y);
                a[6] = (short)f2bf(hi.z); a[7] = (short)f2bf(hi.w);
            } else {       // k>=128: maxes bf16 direct
                a = *reinterpret_cast<const short8*>(
                    maxes + (size_t)rA[t] * WIDTH + (koff - 128));
            }
            acc[t][0] = __builtin_amdgcn_mfma_f32_16x16x32_bf16(a, b0, acc[t][0], 0, 0, 0);
            acc[t][1] = __builtin_amdgcn_mfma_f32_16x16x32_bf16(a, b1, acc[t][1], 0, 0, 0);
        }
    }

    float bia0 = bias[ncol0 + l15];
    float bia1 = bias[ncol0 + 16 + l15];
    #pragma unroll
    for (int t = 0; t < 4; ++t) {
        #pragma unroll
        for (int u = 0; u < 2; ++u) {
            int col = ncol0 + u * 16 + l15;
            float bb = u ? bia1 : bia0;
            #pragma unroll
            for (int r = 0; r < 4; ++r) {
                int grow = blockRow + t * 16 + q * 4 + r;
                if (grow < M) {
                    float h = acc[t][u][r] + bb;
                    float lr = h > 0.f ? h : SLOPE * h;
                    out[(size_t)grow * WIDTH + col] =
                        x_dst[(size_t)grow * WIDTH + col] + lr;
                }
            }
        }
    }
}

extern "C" void kernel_launch(void* const* d_in, const int* in_sizes, int n_in,
                              void* d_out, int out_size, void* d_ws, size_t ws_size,
                              hipStream_t stream) {
    const float* x_src = (const float*)d_in[0];
    const float* x_dst = (const float*)d_in[1];
    const int*   e     = (const int*)d_in[2];
    const float* W     = (const float*)d_in[3];
    const float* bias  = (const float*)d_in[4];
    float* out = (float*)d_out;

    int E = in_sizes[2] / 2;        // 800000
    int M = in_sizes[1] / WIDTH;    // 100000 dst nodes
    int NB = (M + SBS - 1) / SBS;   // 196 (<= 256)

    // ws: maxes bf16[M*128] | Wt bf16[128*256] | counts[M] | offsets[M+1] |
    //     rank[E] | csr_src[E] | bsums[NB] | bbase[NB]   (~33 MB total)
    unsigned short* maxes = (unsigned short*)d_ws;
    unsigned short* Wt    = maxes + (size_t)M * WIDTH;
    unsigned* counts  = (unsigned*)(Wt + 128 * 256);
    int*      offsets = (int*)(counts + M);
    int*      rank    = offsets + (M + 1);
    int*      csr_src = rank + E;
    unsigned* bsums   = (unsigned*)(csr_src + E);
    unsigned* bbase   = bsums + NB;

    hipMemsetAsync(counts, 0, (size_t)M * sizeof(unsigned), stream);

    int eblocks = (E + 255) / 256;
    hist_kernel<<<eblocks, 256, 0, stream>>>(e, counts, rank, E);
    block_sum_kernel<<<NB, SBS, 0, stream>>>(counts, bsums, M);
    bsum_scan_kernel<<<1, 256, 0, stream>>>(bsums, bbase, NB, offsets, M);
    scan_final_kernel<<<NB, SBS, 0, stream>>>(counts, bbase, offsets, M);
    scatter_kernel<<<eblocks, 256, 0, stream>>>(e, offsets, rank, csr_src, E);
    wt_kernel<<<(128 * 64 + 255) / 256, 256, 0, stream>>>(W, Wt);

    int gblocks = (M + GWAVES - 1) / GWAVES;
    gather_min_kernel<<<gblocks, GWAVES * 64, 0, stream>>>(x_src, x_dst, offsets,
                                                           csr_src, maxes, M);

    int mblocks = (M + GBM - 1) / GBM;
    mfma_gemm_kernel<<<mblocks, 256, 0, stream>>>(x_dst, maxes, Wt, bias, out, M);
}

// Round 6
// 181.723 us; speedup vs baseline: 4.3831x; 1.1052x over previous
//
#include <hip/hip_runtime.h>

#define WIDTH 128
#define SLOPE 0.01f
#define SBS 512
#define GWAVES 8
#define GBM 64

typedef __attribute__((ext_vector_type(8))) short short8;
typedef __attribute__((ext_vector_type(4))) float f32x4;

__device__ __forceinline__ unsigned short f2bf(float f) {
    unsigned b = __float_as_uint(f);
    b += 0x7FFFu + ((b >> 16) & 1u);   // round-to-nearest-even
    return (unsigned short)(b >> 16);
}
__device__ __forceinline__ float4 upk(uint2 u) {   // 4 bf16 -> 4 f32 (exact)
    float4 r;
    r.x = __uint_as_float(u.x << 16);
    r.y = __uint_as_float(u.x & 0xFFFF0000u);
    r.z = __uint_as_float(u.y << 16);
    r.w = __uint_as_float(u.y & 0xFFFF0000u);
    return r;
}
__device__ __forceinline__ float4 fmin4(float4 a, float4 b) {
    return make_float4(fminf(a.x, b.x), fminf(a.y, b.y),
                       fminf(a.z, b.z), fminf(a.w, b.w));
}

// ---------------- CSR build: counting sort of edges by dst ----------------
__global__ void hist_kernel(const int* __restrict__ e,
                            unsigned* __restrict__ counts,
                            int* __restrict__ rank, int E) {
    int i = blockIdx.x * blockDim.x + threadIdx.x;
    if (i < E) {
        int dst = e[E + i];
        rank[i] = (int)atomicAdd(&counts[dst], 1u);
    }
}

__global__ void block_sum_kernel(const unsigned* __restrict__ counts,
                                 unsigned* __restrict__ bsums, int M) {
    int i = blockIdx.x * SBS + threadIdx.x;
    unsigned v = (i < M) ? counts[i] : 0u;
    for (int d = 32; d > 0; d >>= 1) v += __shfl_down(v, d);
    __shared__ unsigned ws[SBS / 64];
    int lane = threadIdx.x & 63, w = threadIdx.x >> 6;
    if (lane == 0) ws[w] = v;
    __syncthreads();
    if (threadIdx.x == 0) {
        unsigned s = 0;
        for (int k = 0; k < SBS / 64; ++k) s += ws[k];
        bsums[blockIdx.x] = s;
    }
}

__global__ void bsum_scan_kernel(const unsigned* __restrict__ bsums,
                                 unsigned* __restrict__ bbase, int NB,
                                 int* __restrict__ offsets, int M) {
    __shared__ unsigned s[256];
    int t = threadIdx.x;
    unsigned v = (t < NB) ? bsums[t] : 0u;
    s[t] = v;
    __syncthreads();
    for (int off = 1; off < 256; off <<= 1) {
        unsigned n = (t >= off) ? s[t - off] : 0u;
        __syncthreads();
        s[t] += n;
        __syncthreads();
    }
    if (t < NB) bbase[t] = s[t] - v;
    if (t == 255) offsets[M] = (int)s[255];
}

__global__ void scan_final_kernel(const unsigned* __restrict__ counts,
                                  const unsigned* __restrict__ bbase,
                                  int* __restrict__ offsets, int M) {
    int b = blockIdx.x, t = threadIdx.x;
    int i = b * SBS + t;
    unsigned c = (i < M) ? counts[i] : 0u;
    unsigned v = c;
    int lane = t & 63, w = t >> 6;
    for (int d = 1; d < 64; d <<= 1) {
        unsigned n = __shfl_up(v, d);
        if (lane >= d) v += n;
    }
    __shared__ unsigned ws[SBS / 64];
    if (lane == 63) ws[w] = v;
    __syncthreads();
    unsigned wbase = 0;
    for (int k = 0; k < w; ++k) wbase += ws[k];
    if (i < M) offsets[i] = (int)(bbase[b] + wbase + v - c);
}

__global__ void scatter_kernel(const int* __restrict__ e,
                               const int* __restrict__ offsets,
                               const int* __restrict__ rank,
                               int* __restrict__ csr_src, int E) {
    int i = blockIdx.x * blockDim.x + threadIdx.x;
    if (i < E) {
        int dst = e[E + i];
        csr_src[offsets[dst] + rank[i]] = e[i];
    }
}

// -------- conv: xb half of ab = bf16(x_dst); xsb = bf16(x_src) -------------
__global__ void conv_kernel(const float* __restrict__ x_src,
                            const float* __restrict__ x_dst,
                            unsigned short* __restrict__ xsb,
                            unsigned short* __restrict__ ab,
                            int NS, int M, int do_xs) {
    int i = blockIdx.x * blockDim.x + threadIdx.x;   // float4 units
    int nds = M * 32;
    if (i < nds) {
        float4 v = reinterpret_cast<const float4*>(x_dst)[i];
        ushort4 o;
        o.x = f2bf(v.x); o.y = f2bf(v.y); o.z = f2bf(v.z); o.w = f2bf(v.w);
        int row = i >> 5, c4 = i & 31;
        *reinterpret_cast<ushort4*>(ab + (size_t)row * 256 + c4 * 4) = o;
    } else if (do_xs) {
        int j = i - nds;
        if (j < NS * 32) {
            float4 v = reinterpret_cast<const float4*>(x_src)[j];
            ushort4 o;
            o.x = f2bf(v.x); o.y = f2bf(v.y); o.z = f2bf(v.z); o.w = f2bf(v.w);
            *reinterpret_cast<ushort4*>(xsb + (size_t)j * 4) = o;
        }
    }
}

// -------- W fold + transpose: A=[xb,mnb] => W'=[W0+W1; -W1], Wt[n][k] ------
__global__ void wt_kernel(const float* __restrict__ W,
                          unsigned short* __restrict__ Wt) {
    int t = blockIdx.x * blockDim.x + threadIdx.x;
    if (t >= 128 * 64) return;
    int n = t & 127, kc = t >> 7;   // kc: 0..63, k = kc*4+j over 0..255
    ushort4 o;
    unsigned short* op = &o.x;
    #pragma unroll
    for (int j = 0; j < 4; ++j) {
        int k = kc * 4 + j;
        float v;
        if (k < 128) v = W[(size_t)k * 128 + n] + W[(size_t)(k + 128) * 128 + n];
        else         v = -W[(size_t)k * 128 + n];
        op[j] = f2bf(v);
    }
    *reinterpret_cast<ushort4*>(Wt + (size_t)n * 256 + kc * 4) = o;
}

// ---------------- Gather + min -> ab[:,128:256] = bf16(min) ----------------
// One wave per TWO dst rows (interleaved chains, 8 gathers in flight).
// 8 edges per row-iteration, 2 edges per load via 32-lane halves.
template<int XSB>
__device__ __forceinline__ void gstep(const float* xs_f,
                                      const unsigned short* xs_b,
                                      const int* csr, int p, int lim,
                                      int half, int cl, float4& mn) {
    int i0 = csr[min(p + 0, lim)];
    int i1 = csr[min(p + 1, lim)];
    int i2 = csr[min(p + 2, lim)];
    int i3 = csr[min(p + 3, lim)];
    int i4 = csr[min(p + 4, lim)];
    int i5 = csr[min(p + 5, lim)];
    int i6 = csr[min(p + 6, lim)];
    int i7 = csr[min(p + 7, lim)];
    int a0 = half ? i1 : i0;
    int a1 = half ? i3 : i2;
    int a2 = half ? i5 : i4;
    int a3 = half ? i7 : i6;
    float4 w0, w1, w2, w3;
    if (XSB) {
        uint2 u0 = *reinterpret_cast<const uint2*>(xs_b + (size_t)a0 * 128 + cl * 4);
        uint2 u1 = *reinterpret_cast<const uint2*>(xs_b + (size_t)a1 * 128 + cl * 4);
        uint2 u2 = *reinterpret_cast<const uint2*>(xs_b + (size_t)a2 * 128 + cl * 4);
        uint2 u3 = *reinterpret_cast<const uint2*>(xs_b + (size_t)a3 * 128 + cl * 4);
        w0 = upk(u0); w1 = upk(u1); w2 = upk(u2); w3 = upk(u3);
    } else {
        const float4* xs4 = reinterpret_cast<const float4*>(xs_f);
        w0 = xs4[(size_t)a0 * 32 + cl];
        w1 = xs4[(size_t)a1 * 32 + cl];
        w2 = xs4[(size_t)a2 * 32 + cl];
        w3 = xs4[(size_t)a3 * 32 + cl];
    }
    mn = fmin4(mn, fmin4(fmin4(w0, w1), fmin4(w2, w3)));
}

template<int XSB>
__global__ void gather_min_kernel(const float* __restrict__ xs_f,
                                  const unsigned short* __restrict__ xs_b,
                                  const int* __restrict__ offsets,
                                  const int* __restrict__ csr,
                                  unsigned short* __restrict__ ab, int M) {
    int lane = threadIdx.x & 63;
    int wv = threadIdx.x >> 6;
    int half = lane >> 5, cl = lane & 31;
    int r0 = __builtin_amdgcn_readfirstlane(2 * (blockIdx.x * GWAVES + wv));
    int r1 = r0 + 1;
    if (r0 >= M) return;
    int beg0 = offsets[r0], end0 = offsets[r0 + 1];
    int beg1 = offsets[r1], end1 = offsets[r1 + 1];

    float4 mn0 = make_float4(INFINITY, INFINITY, INFINITY, INFINITY);
    float4 mn1 = mn0;
    int p0 = beg0, p1 = beg1;
    while (p0 < end0 || p1 < end1) {
        if (p0 < end0) { gstep<XSB>(xs_f, xs_b, csr, p0, end0 - 1, half, cl, mn0); p0 += 8; }
        if (p1 < end1) { gstep<XSB>(xs_f, xs_b, csr, p1, end1 - 1, half, cl, mn1); p1 += 8; }
    }
    // fold the two 32-lane halves (different edges, same columns)
    mn0.x = fminf(mn0.x, __shfl_xor(mn0.x, 32));
    mn0.y = fminf(mn0.y, __shfl_xor(mn0.y, 32));
    mn0.z = fminf(mn0.z, __shfl_xor(mn0.z, 32));
    mn0.w = fminf(mn0.w, __shfl_xor(mn0.w, 32));
    mn1.x = fminf(mn1.x, __shfl_xor(mn1.x, 32));
    mn1.y = fminf(mn1.y, __shfl_xor(mn1.y, 32));
    mn1.z = fminf(mn1.z, __shfl_xor(mn1.z, 32));
    mn1.w = fminf(mn1.w, __shfl_xor(mn1.w, 32));

    // lanes 0-31 write row r0's mn-half, lanes 32-63 write row r1's
    int wr = half ? r1 : r0;
    bool has = half ? (beg1 < end1) : (beg0 < end0);
    float4 m;
    m.x = half ? mn1.x : mn0.x;
    m.y = half ? mn1.y : mn0.y;
    m.z = half ? mn1.z : mn0.z;
    m.w = half ? mn1.w : mn0.w;
    ushort4 o;
    if (has) {
        o.x = f2bf(m.x); o.y = f2bf(m.y); o.z = f2bf(m.z); o.w = f2bf(m.w);
    } else {
        // empty row: mnb := xb  =>  xb@(W0+W1) - mnb@W1 == xb@W0 exactly
        o = *reinterpret_cast<const ushort4*>(ab + (size_t)wr * 256 + cl * 4);
    }
    *reinterpret_cast<ushort4*>(ab + (size_t)wr * 256 + 128 + cl * 4) = o;
}

// ------- MFMA GEMM (swapped operands => float4 epilogue) -------------------
// h^T = W't · ab^T ; out = xb + lrelu(h).  64 rows/block, 4 waves x 32 cols.
__global__ __launch_bounds__(256) void mfma_gemm_kernel(
        const unsigned short* __restrict__ ab,
        const unsigned short* __restrict__ Wt,
        const float* __restrict__ bias,
        float* __restrict__ out, int M) {
    int lane = threadIdx.x & 63;
    int wv = threadIdx.x >> 6;
    int l15 = lane & 15;
    int q = lane >> 4;
    int blockRow = blockIdx.x * GBM;
    int ncol0 = wv * 32;

    f32x4 acc[4][2];
    #pragma unroll
    for (int t = 0; t < 4; ++t) {
        acc[t][0] = (f32x4){0.f, 0.f, 0.f, 0.f};
        acc[t][1] = (f32x4){0.f, 0.f, 0.f, 0.f};
    }

    size_t aoff[4];
    #pragma unroll
    for (int t = 0; t < 4; ++t)
        aoff[t] = (size_t)min(blockRow + t * 16 + l15, M - 1) * 256;
    size_t b0off = (size_t)(ncol0 + l15) * 256;
    size_t b1off = (size_t)(ncol0 + 16 + l15) * 256;

    #pragma unroll
    for (int s = 0; s < 8; ++s) {
        int koff = s * 32 + q * 8;
        short8 b0 = *reinterpret_cast<const short8*>(Wt + b0off + koff);
        short8 b1 = *reinterpret_cast<const short8*>(Wt + b1off + koff);
        #pragma unroll
        for (int t = 0; t < 4; ++t) {
            short8 a = *reinterpret_cast<const short8*>(ab + aoff[t] + koff);
            // swapped: result lane l15 = A-row (out row), regs = 4 consecutive cols
            acc[t][0] = __builtin_amdgcn_mfma_f32_16x16x32_bf16(b0, a, acc[t][0], 0, 0, 0);
            acc[t][1] = __builtin_amdgcn_mfma_f32_16x16x32_bf16(b1, a, acc[t][1], 0, 0, 0);
        }
    }

    float4 bi[2];
    bi[0] = *reinterpret_cast<const float4*>(bias + ncol0 + q * 4);
    bi[1] = *reinterpret_cast<const float4*>(bias + ncol0 + 16 + q * 4);
    #pragma unroll
    for (int t = 0; t < 4; ++t) {
        int row = blockRow + t * 16 + l15;
        if (row < M) {
            #pragma unroll
            for (int u = 0; u < 2; ++u) {
                int col = ncol0 + u * 16 + q * 4;
                uint2 xu = *reinterpret_cast<const uint2*>(ab + (size_t)row * 256 + col);
                float4 xb = upk(xu);
                float4 o;
                float h;
                h = acc[t][u][0] + bi[u].x; o.x = xb.x + (h > 0.f ? h : SLOPE * h);
                h = acc[t][u][1] + bi[u].y; o.y = xb.y + (h > 0.f ? h : SLOPE * h);
                h = acc[t][u][2] + bi[u].z; o.z = xb.z + (h > 0.f ? h : SLOPE * h);
                h = acc[t][u][3] + bi[u].w; o.w = xb.w + (h > 0.f ? h : SLOPE * h);
                *reinterpret_cast<float4*>(out + (size_t)row * 128 + col) = o;
            }
        }
    }
}

extern "C" void kernel_launch(void* const* d_in, const int* in_sizes, int n_in,
                              void* d_out, int out_size, void* d_ws, size_t ws_size,
                              hipStream_t stream) {
    const float* x_src = (const float*)d_in[0];
    const float* x_dst = (const float*)d_in[1];
    const int*   e     = (const int*)d_in[2];
    const float* W     = (const float*)d_in[3];
    const float* bias  = (const float*)d_in[4];
    float* out = (float*)d_out;

    int NS = in_sizes[0] / WIDTH;   // 100000 src nodes
    int E  = in_sizes[2] / 2;       // 800000
    int M  = in_sizes[1] / WIDTH;   // 100000 dst nodes
    int NB = (M + SBS - 1) / SBS;   // 196 (<= 256)

    // ws: ab bf16[M*256] | Wt bf16[128*256] | counts[M] | offsets[M+1] |
    //     rank[E] | csr[E] | bsums | bbase | xsb bf16[NS*128] (optional)
    unsigned short* ab = (unsigned short*)d_ws;
    unsigned short* Wt = ab + (size_t)M * 256;
    unsigned* counts  = (unsigned*)(Wt + 128 * 256);
    int*      offsets = (int*)(counts + M);
    int*      rank    = offsets + (M + 1);
    int*      csr     = rank + E;
    unsigned* bsums   = (unsigned*)(csr + E);
    unsigned* bbase   = bsums + NB;
    unsigned short* xsb = (unsigned short*)(bbase + NB);
    size_t need_xsb = (char*)(xsb + (size_t)NS * WIDTH) - (char*)d_ws;
    int use_xsb = (ws_size >= need_xsb) ? 1 : 0;

    hipMemsetAsync(counts, 0, (size_t)M * sizeof(unsigned), stream);

    int eblocks = (E + 255) / 256;
    hist_kernel<<<eblocks, 256, 0, stream>>>(e, counts, rank, E);
    block_sum_kernel<<<NB, SBS, 0, stream>>>(counts, bsums, M);
    bsum_scan_kernel<<<1, 256, 0, stream>>>(bsums, bbase, NB, offsets, M);
    scan_final_kernel<<<NB, SBS, 0, stream>>>(counts, bbase, offsets, M);
    scatter_kernel<<<eblocks, 256, 0, stream>>>(e, offsets, rank, csr, E);

    int cunits = M * 32 + (use_xsb ? NS * 32 : 0);
    conv_kernel<<<(cunits + 255) / 256, 256, 0, stream>>>(x_src, x_dst, xsb, ab,
                                                          NS, M, use_xsb);
    wt_kernel<<<(128 * 64 + 255) / 256, 256, 0, stream>>>(W, Wt);

    int gblocks = (M / 2 + GWAVES - 1) / GWAVES;
    if (use_xsb)
        gather_min_kernel<1><<<gblocks, GWAVES * 64, 0, stream>>>(x_src, xsb, offsets,
                                                                  csr, ab, M);
    else
        gather_min_kernel<0><<<gblocks, GWAVES * 64, 0, stream>>>(x_src, xsb, offsets,
                                                                  csr, ab, M);

    int mblocks = (M + GBM - 1) / GBM;
    mfma_gemm_kernel<<<mblocks, 256, 0, stream>>>(ab, Wt, bias, out, M);
}

// Round 7
// 139.512 us; speedup vs baseline: 5.7092x; 1.3026x over previous
//
#include <hip/hip_runtime.h>

#define WIDTH 128
#define SLOPE 0.01f
#define SBS 512
#define FBM 64

typedef __attribute__((ext_vector_type(8))) short short8;
typedef __attribute__((ext_vector_type(4))) float f32x4;

__device__ __forceinline__ unsigned short f2bf(float f) {
    unsigned b = __float_as_uint(f);
    b += 0x7FFFu + ((b >> 16) & 1u);   // round-to-nearest-even
    return (unsigned short)(b >> 16);
}
__device__ __forceinline__ float4 upk(uint2 u) {   // 4 bf16 -> 4 f32 (exact)
    float4 r;
    r.x = __uint_as_float(u.x << 16);
    r.y = __uint_as_float(u.x & 0xFFFF0000u);
    r.z = __uint_as_float(u.y << 16);
    r.w = __uint_as_float(u.y & 0xFFFF0000u);
    return r;
}
__device__ __forceinline__ float4 fmin4(float4 a, float4 b) {
    return make_float4(fminf(a.x, b.x), fminf(a.y, b.y),
                       fminf(a.z, b.z), fminf(a.w, b.w));
}
// XOR-swizzled LDS byte offset for row-major [64][512B] tile (T2/G4: 2-way, free)
__device__ __forceinline__ int swz(int lr, int bc) {
    return lr * 512 + (bc ^ ((lr & 7) << 4));
}

// ---------------- prep: xsb = bf16(x_src)  |  hist  |  W fold+transpose ----
__global__ void prep_kernel(const float* __restrict__ x_src,
                            const float* __restrict__ W,
                            const int* __restrict__ e,
                            unsigned short* __restrict__ xsb,
                            unsigned short* __restrict__ Wt,
                            unsigned* __restrict__ counts,
                            int* __restrict__ rank,
                            int NS, int E, int nconv, int nhist) {
    int b = blockIdx.x;
    if (b < nconv) {
        int i = b * 256 + threadIdx.x;          // float4 units over x_src
        if (i < NS * 32) {
            float4 v = reinterpret_cast<const float4*>(x_src)[i];
            ushort4 o;
            o.x = f2bf(v.x); o.y = f2bf(v.y); o.z = f2bf(v.z); o.w = f2bf(v.w);
            *reinterpret_cast<ushort4*>(xsb + (size_t)i * 4) = o;
        }
    } else if (b < nconv + nhist) {
        int i = (b - nconv) * 256 + threadIdx.x;
        if (i < E) {
            int dst = e[E + i];
            rank[i] = (int)atomicAdd(&counts[dst], 1u);
        }
    } else {
        int t = (b - nconv - nhist) * 256 + threadIdx.x;
        if (t < 128 * 64) {
            int n = t & 127, kc = t >> 7;       // k = kc*4+j over 0..255
            ushort4 o;
            unsigned short* op = &o.x;
            #pragma unroll
            for (int j = 0; j < 4; ++j) {
                int k = kc * 4 + j;
                float v;
                if (k < 128) v = W[(size_t)k * 128 + n] + W[(size_t)(k + 128) * 128 + n];
                else         v = -W[(size_t)k * 128 + n];
                op[j] = f2bf(v);
            }
            *reinterpret_cast<ushort4*>(Wt + (size_t)n * 256 + kc * 4) = o;
        }
    }
}

// ---------------- scan + scatter (counting sort by dst) --------------------
__global__ void block_sum_kernel(const unsigned* __restrict__ counts,
                                 unsigned* __restrict__ bsums, int M) {
    int i = blockIdx.x * SBS + threadIdx.x;
    unsigned v = (i < M) ? counts[i] : 0u;
    for (int d = 32; d > 0; d >>= 1) v += __shfl_down(v, d);
    __shared__ unsigned ws[SBS / 64];
    int lane = threadIdx.x & 63, w = threadIdx.x >> 6;
    if (lane == 0) ws[w] = v;
    __syncthreads();
    if (threadIdx.x == 0) {
        unsigned s = 0;
        for (int k = 0; k < SBS / 64; ++k) s += ws[k];
        bsums[blockIdx.x] = s;
    }
}

__global__ void bsum_scan_kernel(const unsigned* __restrict__ bsums,
                                 unsigned* __restrict__ bbase, int NB,
                                 int* __restrict__ offsets, int M) {
    __shared__ unsigned s[256];
    int t = threadIdx.x;
    unsigned v = (t < NB) ? bsums[t] : 0u;
    s[t] = v;
    __syncthreads();
    for (int off = 1; off < 256; off <<= 1) {
        unsigned n = (t >= off) ? s[t - off] : 0u;
        __syncthreads();
        s[t] += n;
        __syncthreads();
    }
    if (t < NB) bbase[t] = s[t] - v;
    if (t == 255) offsets[M] = (int)s[255];
}

__global__ void scan_final_kernel(const unsigned* __restrict__ counts,
                                  const unsigned* __restrict__ bbase,
                                  int* __restrict__ offsets, int M) {
    int b = blockIdx.x, t = threadIdx.x;
    int i = b * SBS + t;
    unsigned c = (i < M) ? counts[i] : 0u;
    unsigned v = c;
    int lane = t & 63, w = t >> 6;
    for (int d = 1; d < 64; d <<= 1) {
        unsigned n = __shfl_up(v, d);
        if (lane >= d) v += n;
    }
    __shared__ unsigned ws[SBS / 64];
    if (lane == 63) ws[w] = v;
    __syncthreads();
    unsigned wbase = 0;
    for (int k = 0; k < w; ++k) wbase += ws[k];
    if (i < M) offsets[i] = (int)(bbase[b] + wbase + v - c);
}

__global__ void scatter_kernel(const int* __restrict__ e,
                               const int* __restrict__ offsets,
                               const int* __restrict__ rank,
                               int* __restrict__ csr, int E) {
    int i = blockIdx.x * blockDim.x + threadIdx.x;
    if (i < E) {
        int dst = e[E + i];
        csr[offsets[dst] + rank[i]] = e[i];
    }
}

// -------- 8-edge gather-min step for one row (2 edges/load, lane halves) ---
template<int XSB>
__device__ __forceinline__ void gstep(const float* xs_f,
                                      const unsigned short* xs_b,
                                      const int* csr, int p, int lim,
                                      int half, int cl, float4& mn) {
    int i0 = csr[min(p + 0, lim)];
    int i1 = csr[min(p + 1, lim)];
    int i2 = csr[min(p + 2, lim)];
    int i3 = csr[min(p + 3, lim)];
    int i4 = csr[min(p + 4, lim)];
    int i5 = csr[min(p + 5, lim)];
    int i6 = csr[min(p + 6, lim)];
    int i7 = csr[min(p + 7, lim)];
    int a0 = half ? i1 : i0;
    int a1 = half ? i3 : i2;
    int a2 = half ? i5 : i4;
    int a3 = half ? i7 : i6;
    float4 w0, w1, w2, w3;
    if (XSB) {
        uint2 u0 = *reinterpret_cast<const uint2*>(xs_b + (size_t)a0 * 128 + cl * 4);
        uint2 u1 = *reinterpret_cast<const uint2*>(xs_b + (size_t)a1 * 128 + cl * 4);
        uint2 u2 = *reinterpret_cast<const uint2*>(xs_b + (size_t)a2 * 128 + cl * 4);
        uint2 u3 = *reinterpret_cast<const uint2*>(xs_b + (size_t)a3 * 128 + cl * 4);
        w0 = upk(u0); w1 = upk(u1); w2 = upk(u2); w3 = upk(u3);
    } else {
        const float4* xs4 = reinterpret_cast<const float4*>(xs_f);
        w0 = xs4[(size_t)a0 * 32 + cl];
        w1 = xs4[(size_t)a1 * 32 + cl];
        w2 = xs4[(size_t)a2 * 32 + cl];
        w3 = xs4[(size_t)a3 * 32 + cl];
    }
    mn = fmin4(mn, fmin4(fmin4(w0, w1), fmin4(w2, w3)));
}

// ---------------- Fused: stage xb + gather-min -> LDS -> MFMA GEMM ---------
// Block = 64 rows, 4 waves. A = [bf16(x_dst) | mn] in XOR-swizzled LDS.
// h^T = W't · A^T ; out = xb + lrelu(h + b).
template<int XSB>
__global__ __launch_bounds__(256, 4) void fused_kernel(
        const float* __restrict__ x_src,
        const unsigned short* __restrict__ xsb,
        const float* __restrict__ x_dst,
        const int* __restrict__ offsets,
        const int* __restrict__ csr,
        const unsigned short* __restrict__ Wt,
        const float* __restrict__ bias,
        float* __restrict__ out, int M) {
    __shared__ unsigned short At[FBM * 256];   // 32 KB
    char* Ab = reinterpret_cast<char*>(At);
    int tid = threadIdx.x;
    int lane = tid & 63;
    int wv = tid >> 6;
    int blockRow = blockIdx.x * FBM;

    // ---- phase 1a: xb = bf16(x_dst) into A[:, 0:128] (coalesced) ----
    #pragma unroll
    for (int i = 0; i < 8; ++i) {
        int u = tid + 256 * i;              // float4 unit
        int lr = u >> 5;                    // 0..63
        int c4 = u & 31;
        int gr = min(blockRow + lr, M - 1);
        float4 v = reinterpret_cast<const float4*>(x_dst)[(size_t)gr * 32 + c4];
        ushort4 o;
        o.x = f2bf(v.x); o.y = f2bf(v.y); o.z = f2bf(v.z); o.w = f2bf(v.w);
        *reinterpret_cast<ushort4*>(Ab + swz(lr, c4 * 8)) = o;
    }
    __syncthreads();

    // ---- phase 1b: gather-min, 16 rows/wave, 4-row interleave ----
    int half = lane >> 5, cl = lane & 31;
    for (int j = 0; j < 4; ++j) {
        int lrb = wv * 16 + 4 * j;
        int beg0, beg1, beg2, beg3, end0, end1, end2, end3;
        {
            int r = __builtin_amdgcn_readfirstlane(blockRow + lrb);
            beg0 = (r + 0 < M) ? offsets[r + 0] : 0;
            end0 = (r + 0 < M) ? offsets[r + 1] : 0;
            beg1 = (r + 1 < M) ? offsets[r + 1] : 0;
            end1 = (r + 1 < M) ? offsets[r + 2] : 0;
            beg2 = (r + 2 < M) ? offsets[r + 2] : 0;
            end2 = (r + 2 < M) ? offsets[r + 3] : 0;
            beg3 = (r + 3 < M) ? offsets[r + 3] : 0;
            end3 = (r + 3 < M) ? offsets[r + 4] : 0;
        }
        float4 mn0 = make_float4(INFINITY, INFINITY, INFINITY, INFINITY);
        float4 mn1 = mn0, mn2 = mn0, mn3 = mn0;
        int p0 = beg0, p1 = beg1, p2 = beg2, p3 = beg3;
        while ((p0 < end0) | (p1 < end1) | (p2 < end2) | (p3 < end3)) {
            if (p0 < end0) { gstep<XSB>(x_src, xsb, csr, p0, end0 - 1, half, cl, mn0); p0 += 8; }
            if (p1 < end1) { gstep<XSB>(x_src, xsb, csr, p1, end1 - 1, half, cl, mn1); p1 += 8; }
            if (p2 < end2) { gstep<XSB>(x_src, xsb, csr, p2, end2 - 1, half, cl, mn2); p2 += 8; }
            if (p3 < end3) { gstep<XSB>(x_src, xsb, csr, p3, end3 - 1, half, cl, mn3); p3 += 8; }
        }
        mn0.x = fminf(mn0.x, __shfl_xor(mn0.x, 32));
        mn0.y = fminf(mn0.y, __shfl_xor(mn0.y, 32));
        mn0.z = fminf(mn0.z, __shfl_xor(mn0.z, 32));
        mn0.w = fminf(mn0.w, __shfl_xor(mn0.w, 32));
        mn1.x = fminf(mn1.x, __shfl_xor(mn1.x, 32));
        mn1.y = fminf(mn1.y, __shfl_xor(mn1.y, 32));
        mn1.z = fminf(mn1.z, __shfl_xor(mn1.z, 32));
        mn1.w = fminf(mn1.w, __shfl_xor(mn1.w, 32));
        mn2.x = fminf(mn2.x, __shfl_xor(mn2.x, 32));
        mn2.y = fminf(mn2.y, __shfl_xor(mn2.y, 32));
        mn2.z = fminf(mn2.z, __shfl_xor(mn2.z, 32));
        mn2.w = fminf(mn2.w, __shfl_xor(mn2.w, 32));
        mn3.x = fminf(mn3.x, __shfl_xor(mn3.x, 32));
        mn3.y = fminf(mn3.y, __shfl_xor(mn3.y, 32));
        mn3.z = fminf(mn3.z, __shfl_xor(mn3.z, 32));
        mn3.w = fminf(mn3.w, __shfl_xor(mn3.w, 32));

        // write pair (0,1): lanes<32 -> row lrb, lanes>=32 -> row lrb+1
        {
            int lr = lrb + half;
            bool has = half ? (end1 > beg1) : (end0 > beg0);
            float4 m = half ? mn1 : mn0;
            ushort4 o;
            if (has) {
                o.x = f2bf(m.x); o.y = f2bf(m.y); o.z = f2bf(m.z); o.w = f2bf(m.w);
            } else {   // empty row: mn := xb  =>  h = xb@W0 exactly
                o = *reinterpret_cast<const ushort4*>(Ab + swz(lr, cl * 8));
            }
            *reinterpret_cast<ushort4*>(Ab + swz(lr, 256 + cl * 8)) = o;
        }
        // write pair (2,3)
        {
            int lr = lrb + 2 + half;
            bool has = half ? (end3 > beg3) : (end2 > beg2);
            float4 m = half ? mn3 : mn2;
            ushort4 o;
            if (has) {
                o.x = f2bf(m.x); o.y = f2bf(m.y); o.z = f2bf(m.z); o.w = f2bf(m.w);
            } else {
                o = *reinterpret_cast<const ushort4*>(Ab + swz(lr, cl * 8));
            }
            *reinterpret_cast<ushort4*>(Ab + swz(lr, 256 + cl * 8)) = o;
        }
    }
    __syncthreads();

    // ---- phase 2: MFMA GEMM, A from LDS, B (folded W') from L2 ----
    int l15 = lane & 15;
    int q = lane >> 4;
    int ncol0 = wv * 32;

    f32x4 acc[4][2];
    #pragma unroll
    for (int t = 0; t < 4; ++t) {
        acc[t][0] = (f32x4){0.f, 0.f, 0.f, 0.f};
        acc[t][1] = (f32x4){0.f, 0.f, 0.f, 0.f};
    }
    size_t b0off = (size_t)(ncol0 + l15) * 256;
    size_t b1off = (size_t)(ncol0 + 16 + l15) * 256;

    #pragma unroll
    for (int s = 0; s < 8; ++s) {
        int koff = s * 32 + q * 8;               // bf16 elements
        short8 b0 = *reinterpret_cast<const short8*>(Wt + b0off + koff);
        short8 b1 = *reinterpret_cast<const short8*>(Wt + b1off + koff);
        #pragma unroll
        for (int t = 0; t < 4; ++t) {
            int lr = t * 16 + l15;
            short8 a = *reinterpret_cast<const short8*>(Ab + swz(lr, koff * 2));
            // swapped operands: C col(lane&15)=out row, C row(q*4+reg)=out col
            acc[t][0] = __builtin_amdgcn_mfma_f32_16x16x32_bf16(b0, a, acc[t][0], 0, 0, 0);
            acc[t][1] = __builtin_amdgcn_mfma_f32_16x16x32_bf16(b1, a, acc[t][1], 0, 0, 0);
        }
    }

    float4 bi[2];
    bi[0] = *reinterpret_cast<const float4*>(bias + ncol0 + q * 4);
    bi[1] = *reinterpret_cast<const float4*>(bias + ncol0 + 16 + q * 4);
    #pragma unroll
    for (int t = 0; t < 4; ++t) {
        int lr = t * 16 + l15;
        int row = blockRow + lr;
        if (row < M) {
            #pragma unroll
            for (int u = 0; u < 2; ++u) {
                int col = ncol0 + u * 16 + q * 4;
                uint2 xu = *reinterpret_cast<const uint2*>(Ab + swz(lr, col * 2));
                float4 xb = upk(xu);
                float4 o;
                float h;
                h = acc[t][u][0] + bi[u].x; o.x = xb.x + (h > 0.f ? h : SLOPE * h);
                h = acc[t][u][1] + bi[u].y; o.y = xb.y + (h > 0.f ? h : SLOPE * h);
                h = acc[t][u][2] + bi[u].z; o.z = xb.z + (h > 0.f ? h : SLOPE * h);
                h = acc[t][u][3] + bi[u].w; o.w = xb.w + (h > 0.f ? h : SLOPE * h);
                *reinterpret_cast<float4*>(out + (size_t)row * 128 + col) = o;
            }
        }
    }
}

extern "C" void kernel_launch(void* const* d_in, const int* in_sizes, int n_in,
                              void* d_out, int out_size, void* d_ws, size_t ws_size,
                              hipStream_t stream) {
    const float* x_src = (const float*)d_in[0];
    const float* x_dst = (const float*)d_in[1];
    const int*   e     = (const int*)d_in[2];
    const float* W     = (const float*)d_in[3];
    const float* bias  = (const float*)d_in[4];
    float* out = (float*)d_out;

    int NS = in_sizes[0] / WIDTH;   // 100000 src nodes
    int E  = in_sizes[2] / 2;       // 800000
    int M  = in_sizes[1] / WIDTH;   // 100000 dst nodes
    int NB = (M + SBS - 1) / SBS;   // 196 (<= 256)

    // ws: xsb bf16[NS*128] | Wt bf16[128*256] | counts[M] | offsets[M+1] |
    //     rank[E] | csr[E] | bsums[NB] | bbase[NB]    (~33 MB)
    unsigned short* xsb = (unsigned short*)d_ws;
    unsigned short* Wt  = xsb + (size_t)NS * WIDTH;
    unsigned* counts  = (unsigned*)(Wt + 128 * 256);
    int*      offsets = (int*)(counts + M);
    int*      rank    = offsets + (M + 1);
    int*      csr     = rank + E;
    unsigned* bsums   = (unsigned*)(csr + E);
    unsigned* bbase   = bsums + NB;
    size_t need = (char*)(bbase + NB) - (char*)d_ws;
    int use_xsb = (ws_size >= need) ? 1 : 0;
    if (!use_xsb) {   // fallback: no xsb; shift layout to skip it
        Wt = (unsigned short*)d_ws;
        counts  = (unsigned*)(Wt + 128 * 256);
        offsets = (int*)(counts + M);
        rank    = offsets + (M + 1);
        csr     = rank + E;
        bsums   = (unsigned*)(csr + E);
        bbase   = bsums + NB;
    }

    hipMemsetAsync(counts, 0, (size_t)M * sizeof(unsigned), stream);

    int nconv = use_xsb ? (NS * 32 + 255) / 256 : 0;
    int nhist = (E + 255) / 256;
    int nwt   = (128 * 64 + 255) / 256;
    prep_kernel<<<nconv + nhist + nwt, 256, 0, stream>>>(x_src, W, e, xsb, Wt,
                                                         counts, rank, NS, E,
                                                         nconv, nhist);
    block_sum_kernel<<<NB, SBS, 0, stream>>>(counts, bsums, M);
    bsum_scan_kernel<<<1, 256, 0, stream>>>(bsums, bbase, NB, offsets, M);
    scan_final_kernel<<<NB, SBS, 0, stream>>>(counts, bbase, offsets, M);
    scatter_kernel<<<(E + 255) / 256, 256, 0, stream>>>(e, offsets, rank, csr, E);

    int fblocks = (M + FBM - 1) / FBM;
    if (use_xsb)
        fused_kernel<1><<<fblocks, 256, 0, stream>>>(x_src, xsb, x_dst, offsets,
                                                     csr, Wt, bias, out, M);
    else
        fused_kernel<0><<<fblocks, 256, 0, stream>>>(x_src, xsb, x_dst, offsets,
                                                     csr, Wt, bias, out, M);
}